// Round 3
// baseline (404.831 us; speedup 1.0000x reference)
//
#include <hip/hip_runtime.h>
#include <hip/hip_bf16.h>
#include <stdint.h>

// B=4, S=2048, D=1024, H=16, hd=64.
// Inputs bf16 or fp32 (runtime-probed on DEVICE, wave-uniform branch);
// OUTPUT IS FLOAT32. Intermediates bf16 in 64MB workspace.

typedef __bf16 bf16_t;
typedef __attribute__((ext_vector_type(8))) __bf16 bf16x8;
typedef __attribute__((ext_vector_type(4))) __bf16 bf16x4;
typedef __attribute__((ext_vector_type(4))) float f32x4;

#define LOG2E 1.44269504088896340736f
#define SCLF (0.125f * LOG2E)
#define MFMA16(a, b, c) __builtin_amdgcn_mfma_f32_16x16x32_bf16(a, b, c, 0, 0, 0)

__device__ __forceinline__ bf16x8 ld8(const bf16_t* p) {
    return *(const bf16x8*)p;
}
__device__ __forceinline__ bf16x8 cvt8(const float* p) {
    f32x4 a = *(const f32x4*)p;
    f32x4 b = *(const f32x4*)(p + 4);
    bf16x8 r;
    r[0] = (bf16_t)a[0]; r[1] = (bf16_t)a[1]; r[2] = (bf16_t)a[2]; r[3] = (bf16_t)a[3];
    r[4] = (bf16_t)b[0]; r[5] = (bf16_t)b[1]; r[6] = (bf16_t)b[2]; r[7] = (bf16_t)b[3];
    return r;
}

// dtype probe (bf16 vs fp32), wave-uniform. true = fp32.
__device__ __forceinline__ bool probe_f32(const void* w) {
    const uint16_t* u = (const uint16_t*)w;
    int cnt = 0;
#pragma unroll
    for (int i = 0; i < 64; ++i) {
        const int e = (u[i] >> 7) & 0xFF;
        cnt += (e >= 96 && e <= 150) ? 1 : 0;
    }
    return cnt < 56;
}

// async global->LDS, 16B per lane. LDS dest is wave-uniform base + lane*16.
__device__ __forceinline__ void gll16(const bf16_t* g, bf16_t* l) {
    __builtin_amdgcn_global_load_lds(
        (const __attribute__((address_space(1))) void*)g,
        (__attribute__((address_space(3))) void*)l, 16, 0, 0);
}

// ---------------------------------------------------------------------------
// GEMM: C = A[M,K] @ B[N,K]^T, 128x128 tile, BK=32. ONE kernel, runtime
// dtype branch (wave-uniform):
//   bf16 inputs -> m97 structure: global_load_lds width-16 staging.
//   fp32 inputs -> reg-staged cvt path (correctness fallback, not perf).
// EPI==0: C float*, plain [M,N]. EPI==1: C bf16* Q|K split + VT scatter.
// ---------------------------------------------------------------------------
template <int EPI>
__global__ __launch_bounds__(256) void gemm_bt_dual(
    const void* __restrict__ A, const void* __restrict__ B,
    void* __restrict__ C, bf16_t* __restrict__ VT,
    int aFollow, int bFollow,
    int M, int N, int K)
{
    __shared__ __align__(16) bf16_t lsA[128 * 32];
    __shared__ __align__(16) bf16_t lsB[128 * 32];

    const bool f32in = probe_f32(B);

    const int t    = threadIdx.x;
    const int lane = t & 63;
    const int wid  = t >> 6;
    const int quad = lane >> 4;
    const int l15  = lane & 15;
    const int wm   = (wid & 1) * 64;
    const int wn   = (wid >> 1) * 64;
    const int m0   = blockIdx.y * 128;
    const int n0   = blockIdx.x * 128;

    f32x4 acc[4][4];
#pragma unroll
    for (int i = 0; i < 4; ++i)
#pragma unroll
        for (int j = 0; j < 4; ++j) acc[i][j] = (f32x4){0.f, 0.f, 0.f, 0.f};

    if (!f32in) {
        // ------- fast path: pure bf16, global_load_lds staging -------
        const bf16_t* Ar = (const bf16_t*)A + (size_t)(m0 + (t >> 2)) * K + (t & 3) * 8;
        const bf16_t* Br = (const bf16_t*)B + (size_t)(n0 + (t >> 2)) * K + (t & 3) * 8;
        bf16_t* la = lsA + t * 8;
        bf16_t* lb = lsB + t * 8;

        for (int k0 = 0; k0 < K; k0 += 32) {
            __syncthreads();   // previous tile's readers done
            gll16(Ar + k0, la);
            gll16(Ar + (size_t)64 * K + k0, la + 2048);
            gll16(Br + k0, lb);
            gll16(Br + (size_t)64 * K + k0, lb + 2048);
            __syncthreads();   // drains vmcnt: tile visible

            bf16x8 af[4], bfr[4];
#pragma unroll
            for (int i = 0; i < 4; ++i)
                af[i] = ld8(lsA + (wm + i * 16 + l15) * 32 + quad * 8);
#pragma unroll
            for (int j = 0; j < 4; ++j)
                bfr[j] = ld8(lsB + (wn + j * 16 + l15) * 32 + quad * 8);
#pragma unroll
            for (int i = 0; i < 4; ++i)
#pragma unroll
                for (int j = 0; j < 4; ++j)
                    acc[i][j] = MFMA16(af[i], bfr[j], acc[i][j]);
        }
    } else {
        // ------- fallback: fp32 (or mixed) inputs, reg-staged cvt -------
        const bool aF32 = (aFollow != 0);
        const bool bF32 = (bFollow != 0);
        const size_t arow = (size_t)(m0 + (t >> 2));
        const size_t brow = (size_t)(n0 + (t >> 2));
        const int    scol = (t & 3) * 8;
        const bf16_t* Ab = (const bf16_t*)A;
        const bf16_t* Bb = (const bf16_t*)B;
        const float*  Af = (const float*)A;
        const float*  Bf = (const float*)B;

        for (int k0 = 0; k0 < K; k0 += 32) {
            bf16x8 sa0, sa1, sb0, sb1;
            if (aF32) {
                sa0 = cvt8(Af + arow * K + k0 + scol);
                sa1 = cvt8(Af + (arow + 64) * K + k0 + scol);
            } else {
                sa0 = ld8(Ab + arow * K + k0 + scol);
                sa1 = ld8(Ab + (arow + 64) * K + k0 + scol);
            }
            if (bF32) {
                sb0 = cvt8(Bf + brow * K + k0 + scol);
                sb1 = cvt8(Bf + (brow + 64) * K + k0 + scol);
            } else {
                sb0 = ld8(Bb + brow * K + k0 + scol);
                sb1 = ld8(Bb + (brow + 64) * K + k0 + scol);
            }

            __syncthreads();
            *(bf16x8*)(lsA + t * 8)        = sa0;
            *(bf16x8*)(lsA + 2048 + t * 8) = sa1;
            *(bf16x8*)(lsB + t * 8)        = sb0;
            *(bf16x8*)(lsB + 2048 + t * 8) = sb1;
            __syncthreads();

            bf16x8 af[4], bfr[4];
#pragma unroll
            for (int i = 0; i < 4; ++i)
                af[i] = ld8(lsA + (wm + i * 16 + l15) * 32 + quad * 8);
#pragma unroll
            for (int j = 0; j < 4; ++j)
                bfr[j] = ld8(lsB + (wn + j * 16 + l15) * 32 + quad * 8);
#pragma unroll
            for (int i = 0; i < 4; ++i)
#pragma unroll
                for (int j = 0; j < 4; ++j)
                    acc[i][j] = MFMA16(af[i], bfr[j], acc[i][j]);
        }
    }

#pragma unroll
    for (int i = 0; i < 4; ++i) {
        const int row = m0 + wm + i * 16 + quad * 4;
#pragma unroll
        for (int j = 0; j < 4; ++j) {
            const int col = n0 + wn + j * 16 + l15;
#pragma unroll
            for (int r = 0; r < 4; ++r) {
                const int rr = row + r;
                if (EPI == 0) {
                    ((float*)C)[(size_t)rr * N + col] = acc[i][j][r];
                } else {
                    const bf16_t v = (bf16_t)acc[i][j][r];
                    if (col < 2048) {
                        ((bf16_t*)C)[(size_t)rr * 2048 + col] = v;
                    } else {
                        const int c2 = col - 2048;
                        const int h = c2 >> 6, d = c2 & 63;
                        const int b = rr >> 11, s = rr & 2047;
                        VT[((size_t)((b << 4) + h) * 64 + d) * 2048 + s] = v;
                    }
                }
            }
        }
    }
}

// ---------------------------------------------------------------------------
// Flash attention (causal), NO-RESCALE, QBLK=32 per TASK, interleaved
// split-K: the two waves of a pair share one (bh,qt) task, taking key-tiles
// of alternating parity. Partials (o,l) are additive (no-rescale) and merged
// once through LDS. 2048 blocks x 4 waves = 8192 waves -> 8 waves/SIMD
// launched (was 4), longest wave halved (32 steps), K/V L2 traffic unchanged.
// Per-CU step-sum exactly constant: qts {c,c+32} / {31-c,63-c} across the
// 8 aliasing blocks -> 520 wave-steps per CU. bh layout keeps each XCD's
// K/V slice at 4MB (= its L2).
// ---------------------------------------------------------------------------
struct Kfrag { bf16x8 k00, k01, k10, k11; };

__device__ __forceinline__ Kfrag ldk(const bf16_t* Kbase, int key0) {
    const bf16_t* kp = Kbase + (size_t)key0 * 2048;
    Kfrag f;
    f.k00 = ld8(kp);
    f.k01 = ld8(kp + 32);
    f.k10 = ld8(kp + (size_t)16 * 2048);
    f.k11 = ld8(kp + (size_t)16 * 2048 + 32);
    return f;
}

__device__ __forceinline__ bf16x4 expq(f32x4 s, float& lsum) {
    bf16x4 r;
#pragma unroll
    for (int i = 0; i < 4; ++i) {
        const float e = exp2f(s[i] * SCLF);
        r[i] = (bf16_t)e;
        lsum += (float)r[i];
    }
    return r;
}
__device__ __forceinline__ bf16x4 expq_m(f32x4 s, float& lsum, int quad, int l15) {
    bf16x4 r;
#pragma unroll
    for (int i = 0; i < 4; ++i) {
        const float e = (quad * 4 + i <= l15) ? exp2f(s[i] * SCLF) : 0.f;
        r[i] = (bf16_t)e;
        lsum += (float)r[i];
    }
    return r;
}

typedef union { bf16x4 h; int u[2]; } pk2;
typedef union { int u[4]; bf16x8 v; } pk4u;

// C-layout (lane=query l15, keys quad*4+r in p0 / 16+quad*4+r in p1) ->
// A-layout (lane=query l15, keys quad*8..quad*8+7). Lane permutation among
// {i, i+16, i+32, i+48}: 8 bpermutes + 4 selects.
__device__ __forceinline__ bf16x8 xpose(bf16x4 p0, bf16x4 p1, int s0b, int s1b, bool lowsel) {
    pk2 a, b;
    a.h = p0; b.h = p1;
    const int x0 = __builtin_amdgcn_ds_bpermute(s0b, a.u[0]);
    const int y0 = __builtin_amdgcn_ds_bpermute(s0b, b.u[0]);
    const int x1 = __builtin_amdgcn_ds_bpermute(s0b, a.u[1]);
    const int y1 = __builtin_amdgcn_ds_bpermute(s0b, b.u[1]);
    const int x2 = __builtin_amdgcn_ds_bpermute(s1b, a.u[0]);
    const int y2 = __builtin_amdgcn_ds_bpermute(s1b, b.u[0]);
    const int x3 = __builtin_amdgcn_ds_bpermute(s1b, a.u[1]);
    const int y3 = __builtin_amdgcn_ds_bpermute(s1b, b.u[1]);
    pk4u r;
    r.u[0] = lowsel ? x0 : y0;
    r.u[1] = lowsel ? x1 : y1;
    r.u[2] = lowsel ? x2 : y2;
    r.u[3] = lowsel ? x3 : y3;
    return r.v;
}

template <int DIAG>
__device__ __forceinline__ void attn_step(
    const Kfrag& kf, const bf16_t* __restrict__ Vbase, int key0,
    int quad, int l15, int s0b, int s1b, bool lowsel,
    const bf16x8& qa0, const bf16x8& qa1, const bf16x8& qb0, const bf16x8& qb1,
    f32x4 (&oa)[4], f32x4 (&ob)[4], float& la, float& lb)
{
    // V for THIS step: issued before QK^T, consumed after softmax (covered).
    const bf16_t* vp = Vbase + key0;
    const bf16x8 vf0 = ld8(vp);
    const bf16x8 vf1 = ld8(vp + (size_t)16 * 2048);
    const bf16x8 vf2 = ld8(vp + (size_t)32 * 2048);
    const bf16x8 vf3 = ld8(vp + (size_t)48 * 2048);

    const f32x4 Z = (f32x4){0.f, 0.f, 0.f, 0.f};
    f32x4 s0a = Z, s1a = Z, s0b_ = Z, s1b_ = Z;
    // swapped operands: C[row=key (quad*4+r)][col=query (l15)]
    s0a = MFMA16(kf.k00, qa0, s0a); s0a = MFMA16(kf.k01, qa1, s0a);
    s0b_ = MFMA16(kf.k00, qb0, s0b_); s0b_ = MFMA16(kf.k01, qb1, s0b_);
    if (!DIAG) {
        s1a = MFMA16(kf.k10, qa0, s1a); s1a = MFMA16(kf.k11, qa1, s1a);
    }
    s1b_ = MFMA16(kf.k10, qb0, s1b_); s1b_ = MFMA16(kf.k11, qb1, s1b_);

    bf16x4 pa0, pa1, pb0, pb1;
    if (DIAG) {
        pa0 = expq_m(s0a, la, quad, l15);
        pa1 = (bf16x4){(bf16_t)0.f, (bf16_t)0.f, (bf16_t)0.f, (bf16_t)0.f};
        pb0 = expq(s0b_, lb);
        pb1 = expq_m(s1b_, lb, quad, l15);
    } else {
        pa0 = expq(s0a, la); pa1 = expq(s1a, la);
        pb0 = expq(s0b_, lb); pb1 = expq(s1b_, lb);
    }

    const bf16x8 pfa = xpose(pa0, pa1, s0b, s1b, lowsel);
    const bf16x8 pfb = xpose(pb0, pb1, s0b, s1b, lowsel);

    oa[0] = MFMA16(pfa, vf0, oa[0]); ob[0] = MFMA16(pfb, vf0, ob[0]);
    oa[1] = MFMA16(pfa, vf1, oa[1]); ob[1] = MFMA16(pfb, vf1, ob[1]);
    oa[2] = MFMA16(pfa, vf2, oa[2]); ob[2] = MFMA16(pfb, vf2, ob[2]);
    oa[3] = MFMA16(pfa, vf3, oa[3]); ob[3] = MFMA16(pfb, vf3, ob[3]);
}

__global__ __launch_bounds__(256) void attn_kernel(
    const bf16_t* __restrict__ qk, const bf16_t* __restrict__ vt,
    bf16_t* __restrict__ out)
{
    __shared__ float mrg[2][64][34];   // per-pair partial merge (o:32, l:2)

    const int t    = threadIdx.x;
    const int wid  = t >> 6;
    const int lane = t & 63;
    const int quad = lane >> 4;
    const int l15  = lane & 15;

    const int bx    = blockIdx.x;        // 0..2047
    const int u     = bx & 255;          // blocks aliasing mod 256 -> same CU
    const int v_    = bx >> 8;           // 0..7
    const int pairI = wid >> 1;          // 0..1
    const int par   = wid & 1;           // split-K parity

    const int bh = ((u & 15) << 2) | (v_ & 3);   // 0..63; XCD-affine (256%8==0)
    const int c  = u >> 4;                       // 0..15
    const int hi = v_ >> 2;                      // 0..1
    const int cc = hi ? (15 - c) : c;
    const int qt = cc | (hi << 4) | (pairI << 5);  // per-CU step-sum constant
    const int b  = bh >> 4;
    const int h  = bh & 15;
    const int q0 = qt << 5;

    // bpermute source lanes (byte indices)
    const int s0b = ((((quad << 1)) & 3) * 16 + l15) << 2;
    const int s1b = ((((quad << 1) + 1) & 3) * 16 + l15) << 2;
    const bool lowsel = quad < 2;

    const bf16_t* Qp = qk + (size_t)(b * 2048 + q0 + l15) * 2048 + h * 64 + quad * 8;
    const bf16x8 qa0 = ld8(Qp);
    const bf16x8 qa1 = ld8(Qp + 32);
    const bf16x8 qb0 = ld8(Qp + (size_t)16 * 2048);
    const bf16x8 qb1 = ld8(Qp + (size_t)16 * 2048 + 32);

    const bf16_t* Kbase = qk + (size_t)(b * 2048 + l15) * 2048 + 1024 + h * 64 + quad * 8;
    const bf16_t* Vbase = vt + ((size_t)bh * 64 + l15) * 2048 + quad * 8;

    f32x4 oa[4], ob[4];
#pragma unroll
    for (int v = 0; v < 4; ++v) {
        oa[v] = (f32x4){0.f, 0.f, 0.f, 0.f};
        ob[v] = (f32x4){0.f, 0.f, 0.f, 0.f};
    }
    float la = 0.f, lb = 0.f;

    // this wave's tiles: kb = par, par+2, ... (< qt), plus diag if qt%2==par
    const bool dg = ((qt & 1) == par);
    int kb = par;
    if (kb < qt || dg) {
        Kfrag kc = ldk(Kbase, ((kb < qt) ? kb : qt) << 5);
        while (kb < qt) {
            const int nk = (kb + 2 < qt) ? (kb + 2) : qt;   // over-read safe
            Kfrag kn = ldk(Kbase, nk << 5);
            attn_step<0>(kc, Vbase, kb << 5, quad, l15, s0b, s1b, lowsel,
                         qa0, qa1, qb0, qb1, oa, ob, la, lb);
            kc = kn;
            kb += 2;
        }
        if (dg)
            attn_step<1>(kc, Vbase, qt << 5, quad, l15, s0b, s1b, lowsel,
                         qa0, qa1, qb0, qb1, oa, ob, la, lb);
    }

    // merge the pair's partials through LDS (additive: no rescale needed)
    float* m = &mrg[pairI][lane][0];
    if (par == 1) {
#pragma unroll
        for (int v = 0; v < 4; ++v)
#pragma unroll
            for (int r = 0; r < 4; ++r) {
                m[v * 4 + r]      = oa[v][r];
                m[16 + v * 4 + r] = ob[v][r];
            }
        m[32] = la; m[33] = lb;
    }
    __syncthreads();
    if (par == 1) return;

#pragma unroll
    for (int v = 0; v < 4; ++v)
#pragma unroll
        for (int r = 0; r < 4; ++r) {
            oa[v][r] += m[v * 4 + r];
            ob[v][r] += m[16 + v * 4 + r];
        }
    la += m[32]; lb += m[33];

    // l: sum the 4 quad replicas (lanes i, i+16, i+32, i+48)
    la += __shfl_xor(la, 16); la += __shfl_xor(la, 32);
    lb += __shfl_xor(lb, 16); lb += __shfl_xor(lb, 32);
    const float inva = 1.0f / la;
    const float invb = 1.0f / lb;

    const size_t obase = (size_t)(b * 2048 + q0 + quad * 4) * 1024 + h * 64 + l15;
#pragma unroll
    for (int r = 0; r < 4; ++r) {
        const float ia = __shfl(inva, quad * 4 + r);
        const float ib = __shfl(invb, quad * 4 + r);
#pragma unroll
        for (int v = 0; v < 4; ++v) {
            out[obase + (size_t)r * 1024 + v * 16]        = (bf16_t)(oa[v][r] * ia);
            out[obase + (size_t)(16 + r) * 1024 + v * 16] = (bf16_t)(ob[v][r] * ib);
        }
    }
}

// fp32-visible stamp if the workspace is too small.
__global__ void ws_check_kernel(float* out, int code) {
    if (code != 0 && threadIdx.x == 0) out[0] = (float)code;
}

// ---------------------------------------------------------------------------
extern "C" void kernel_launch(void* const* d_in, const int* in_sizes, int n_in,
                              void* d_out, int out_size, void* d_ws, size_t ws_size,
                              hipStream_t stream)
{
    const void* x    = d_in[0];   // [4,2048,1024]
    const void* wqkv = d_in[1];   // [3072,1024]
    const void* wout = d_in[2];   // [1024,1024]

    // ws: qk 32MB | vt 16MB | attn 16MB = 64MB
    bf16_t* qkbuf   = (bf16_t*)d_ws;
    bf16_t* vtbuf   = qkbuf + (size_t)8192 * 2048;
    bf16_t* attnbuf = vtbuf + (size_t)64 * 64 * 2048;
    float*  outp    = (float*)d_out;

    const int wsBad = (ws_size < (size_t)64 * 1024 * 1024) ? 512 : 0;

    // 1) QKV projection: [8192,1024] @ [3072,1024]^T, split Q|K + V^T
    gemm_bt_dual<1><<<dim3(24, 64), 256, 0, stream>>>(
        x, wqkv, qkbuf, vtbuf, 1, 1, 8192, 3072, 1024);

    // 2) causal flash attention: 8192 waves (split-K pairs) = 2048 blocks
    attn_kernel<<<2048, 256, 0, stream>>>(qkbuf, vtbuf, attnbuf);

    // 3) output projection -> fp32 d_out
    gemm_bt_dual<0><<<dim3(8, 64), 256, 0, stream>>>(
        attnbuf, wout, outp, nullptr, 0, 1, 8192, 1024, 1024);

    ws_check_kernel<<<1, 64, 0, stream>>>(outp, wsBad);
}

// Round 4
// 363.787 us; speedup vs baseline: 1.1128x; 1.1128x over previous
//
#include <hip/hip_runtime.h>
#include <hip/hip_bf16.h>
#include <stdint.h>

// B=4, S=2048, D=1024, H=16, hd=64.
// Inputs fp32 (measured: in_npz == fp32 byte count) or bf16; probed in the
// cvt kernels only. Everything downstream is pure bf16. OUTPUT IS FLOAT32.
//
// Buffer plan (64MB ws + d_out-as-scratch):
//   ws:    qk 32MB | vt 16MB | attnbuf 16MB
//   xb  (16MB bf16) -> attnbuf region  (dead before attn writes it)
//   wqb ( 6MB bf16) -> d_out scratch   (dead before gemm2 writes d_out)
//   wob ( 2MB bf16) -> vtbuf region    (converted after attn; vt dead)

typedef __bf16 bf16_t;
typedef __attribute__((ext_vector_type(8))) __bf16 bf16x8;
typedef __attribute__((ext_vector_type(4))) __bf16 bf16x4;
typedef __attribute__((ext_vector_type(4))) float f32x4;

#define LOG2E 1.44269504088896340736f
#define SCLF (0.125f * LOG2E)
#define MFMA16(a, b, c) __builtin_amdgcn_mfma_f32_16x16x32_bf16(a, b, c, 0, 0, 0)

__device__ __forceinline__ bf16x8 ld8(const bf16_t* p) {
    return *(const bf16x8*)p;
}
__device__ __forceinline__ bf16x8 cvt8(const float* p) {
    f32x4 a = *(const f32x4*)p;
    f32x4 b = *(const f32x4*)(p + 4);
    bf16x8 r;
    r[0] = (bf16_t)a[0]; r[1] = (bf16_t)a[1]; r[2] = (bf16_t)a[2]; r[3] = (bf16_t)a[3];
    r[4] = (bf16_t)b[0]; r[5] = (bf16_t)b[1]; r[6] = (bf16_t)b[2]; r[7] = (bf16_t)b[3];
    return r;
}

// dtype probe (bf16 vs fp32), wave-uniform. true = fp32.
__device__ __forceinline__ bool probe_f32(const void* w) {
    const uint16_t* u = (const uint16_t*)w;
    int cnt = 0;
#pragma unroll
    for (int i = 0; i < 64; ++i) {
        const int e = (u[i] >> 7) & 0xFF;
        cnt += (e >= 96 && e <= 150) ? 1 : 0;
    }
    return cnt < 56;
}

// async global->LDS, 16B per lane. LDS dest: wave-uniform base + lane*16.
__device__ __forceinline__ void gll16(const bf16_t* g, bf16_t* l) {
    __builtin_amdgcn_global_load_lds(
        (const __attribute__((address_space(1))) void*)g,
        (__attribute__((address_space(3))) void*)l, 16, 0, 0);
}

// ---------------------------------------------------------------------------
// Input conversion (fp32->bf16, or bf16 copy), 8 elems/thread.
// big: x (1048576 chunks) + W_qkv (393216 chunks) = 5632 blocks x 256.
// small: W_out (131072 chunks) = 512 blocks x 256.
// ---------------------------------------------------------------------------
__global__ __launch_bounds__(256) void cvt_big_kernel(
    const void* __restrict__ x, const void* __restrict__ wq,
    bf16_t* __restrict__ xb, bf16_t* __restrict__ wqb)
{
    const int gid = blockIdx.x * 256 + threadIdx.x;
    const void* src;
    bf16_t* dst;
    int off;
    if (gid < 1048576) { src = x;  dst = xb;  off = gid; }
    else               { src = wq; dst = wqb; off = gid - 1048576; }
    const bool f32 = probe_f32(src);
    const bf16x8 v = f32 ? cvt8((const float*)src + (size_t)off * 8)
                         : ld8((const bf16_t*)src + (size_t)off * 8);
    *(bf16x8*)(dst + (size_t)off * 8) = v;
}

__global__ __launch_bounds__(256) void cvt_small_kernel(
    const void* __restrict__ wo, bf16_t* __restrict__ wob)
{
    const int off = blockIdx.x * 256 + threadIdx.x;
    const bool f32 = probe_f32(wo);
    const bf16x8 v = f32 ? cvt8((const float*)wo + (size_t)off * 8)
                         : ld8((const bf16_t*)wo + (size_t)off * 8);
    *(bf16x8*)(wob + (size_t)off * 8) = v;
}

// ---------------------------------------------------------------------------
// GEMM (pure bf16): C = A[M,K] @ B[N,K]^T, 128x128 tile, BK=32,
// global_load_lds width-16 staging (m97 structure).
// EPI==0: C float*, plain [M,N]. EPI==1: C bf16* Q|K split + VT scatter.
// ---------------------------------------------------------------------------
template <int EPI>
__global__ __launch_bounds__(256) void gemm_bt_lds(
    const bf16_t* __restrict__ A, const bf16_t* __restrict__ B,
    void* __restrict__ C, bf16_t* __restrict__ VT,
    int M, int N, int K)
{
    __shared__ __align__(16) bf16_t lsA[128 * 32];
    __shared__ __align__(16) bf16_t lsB[128 * 32];

    const int t    = threadIdx.x;
    const int lane = t & 63;
    const int wid  = t >> 6;
    const int quad = lane >> 4;
    const int l15  = lane & 15;
    const int wm   = (wid & 1) * 64;
    const int wn   = (wid >> 1) * 64;
    const int m0   = blockIdx.y * 128;
    const int n0   = blockIdx.x * 128;

    // thread t stages 16B: row (t>>2), col (t&3)*8 -> LDS byte t*16 (linear)
    const bf16_t* Ar = A + (size_t)(m0 + (t >> 2)) * K + (t & 3) * 8;
    const bf16_t* Br = B + (size_t)(n0 + (t >> 2)) * K + (t & 3) * 8;
    bf16_t* la = lsA + t * 8;
    bf16_t* lb = lsB + t * 8;

    f32x4 acc[4][4];
#pragma unroll
    for (int i = 0; i < 4; ++i)
#pragma unroll
        for (int j = 0; j < 4; ++j) acc[i][j] = (f32x4){0.f, 0.f, 0.f, 0.f};

    for (int k0 = 0; k0 < K; k0 += 32) {
        __syncthreads();   // previous tile's readers done
        gll16(Ar + k0, la);
        gll16(Ar + (size_t)64 * K + k0, la + 2048);
        gll16(Br + k0, lb);
        gll16(Br + (size_t)64 * K + k0, lb + 2048);
        __syncthreads();   // compiler drains vmcnt before s_barrier: tile visible

        bf16x8 af[4], bfr[4];
#pragma unroll
        for (int i = 0; i < 4; ++i)
            af[i] = ld8(lsA + (wm + i * 16 + l15) * 32 + quad * 8);
#pragma unroll
        for (int j = 0; j < 4; ++j)
            bfr[j] = ld8(lsB + (wn + j * 16 + l15) * 32 + quad * 8);
#pragma unroll
        for (int i = 0; i < 4; ++i)
#pragma unroll
            for (int j = 0; j < 4; ++j)
                acc[i][j] = MFMA16(af[i], bfr[j], acc[i][j]);
    }

#pragma unroll
    for (int i = 0; i < 4; ++i) {
        const int row = m0 + wm + i * 16 + quad * 4;
#pragma unroll
        for (int j = 0; j < 4; ++j) {
            const int col = n0 + wn + j * 16 + l15;
#pragma unroll
            for (int r = 0; r < 4; ++r) {
                const int rr = row + r;
                if (EPI == 0) {
                    ((float*)C)[(size_t)rr * N + col] = acc[i][j][r];
                } else {
                    const bf16_t v = (bf16_t)acc[i][j][r];
                    if (col < 2048) {
                        ((bf16_t*)C)[(size_t)rr * 2048 + col] = v;
                    } else {
                        const int c2 = col - 2048;
                        const int h = c2 >> 6, d = c2 & 63;
                        const int b = rr >> 11, s = rr & 2047;
                        VT[((size_t)((b << 4) + h) * 64 + d) * 2048 + s] = v;
                    }
                }
            }
        }
    }
}

// ---------------------------------------------------------------------------
// Flash attention (causal), NO-RESCALE, QBLK=32 per task, split-K pairs.
// FIX vs R3: block = 128 threads = exactly ONE pair; both waves share the
// SAME (bh,qt) task and differ only in key-tile parity -> the merge barrier
// waits <=1 step (R3 coupled qt and qt+32 in one block: short pair idled at
// the barrier -> regression). Per-CU balance: qts {q2*16+cc} with cc=c or
// 15-c alternating -> sum over aliasing blocks constant (126). bh keeps XCD
// affinity: all blocks of one bh have bx&7 const; 8 bh/XCD -> 4MB K/V = L2.
// 4096 blocks x 2 waves = 8192 waves; critical path 32 steps (R2: 64).
// ---------------------------------------------------------------------------
struct Kfrag { bf16x8 k00, k01, k10, k11; };

__device__ __forceinline__ Kfrag ldk(const bf16_t* Kbase, int key0) {
    const bf16_t* kp = Kbase + (size_t)key0 * 2048;
    Kfrag f;
    f.k00 = ld8(kp);
    f.k01 = ld8(kp + 32);
    f.k10 = ld8(kp + (size_t)16 * 2048);
    f.k11 = ld8(kp + (size_t)16 * 2048 + 32);
    return f;
}

__device__ __forceinline__ bf16x4 expq(f32x4 s, float& lsum) {
    bf16x4 r;
#pragma unroll
    for (int i = 0; i < 4; ++i) {
        const float e = exp2f(s[i] * SCLF);
        r[i] = (bf16_t)e;
        lsum += (float)r[i];
    }
    return r;
}
__device__ __forceinline__ bf16x4 expq_m(f32x4 s, float& lsum, int quad, int l15) {
    bf16x4 r;
#pragma unroll
    for (int i = 0; i < 4; ++i) {
        const float e = (quad * 4 + i <= l15) ? exp2f(s[i] * SCLF) : 0.f;
        r[i] = (bf16_t)e;
        lsum += (float)r[i];
    }
    return r;
}

typedef union { bf16x4 h; int u[2]; } pk2;
typedef union { int u[4]; bf16x8 v; } pk4u;

// C-layout (lane=query l15, keys quad*4+r in p0 / 16+quad*4+r in p1) ->
// A-layout (lane=query l15, keys quad*8..quad*8+7). Lane permutation among
// {i, i+16, i+32, i+48}: 8 bpermutes + 4 selects.
__device__ __forceinline__ bf16x8 xpose(bf16x4 p0, bf16x4 p1, int s0b, int s1b, bool lowsel) {
    pk2 a, b;
    a.h = p0; b.h = p1;
    const int x0 = __builtin_amdgcn_ds_bpermute(s0b, a.u[0]);
    const int y0 = __builtin_amdgcn_ds_bpermute(s0b, b.u[0]);
    const int x1 = __builtin_amdgcn_ds_bpermute(s0b, a.u[1]);
    const int y1 = __builtin_amdgcn_ds_bpermute(s0b, b.u[1]);
    const int x2 = __builtin_amdgcn_ds_bpermute(s1b, a.u[0]);
    const int y2 = __builtin_amdgcn_ds_bpermute(s1b, b.u[0]);
    const int x3 = __builtin_amdgcn_ds_bpermute(s1b, a.u[1]);
    const int y3 = __builtin_amdgcn_ds_bpermute(s1b, b.u[1]);
    pk4u r;
    r.u[0] = lowsel ? x0 : y0;
    r.u[1] = lowsel ? x1 : y1;
    r.u[2] = lowsel ? x2 : y2;
    r.u[3] = lowsel ? x3 : y3;
    return r.v;
}

template <int DIAG>
__device__ __forceinline__ void attn_step(
    const Kfrag& kf, const bf16_t* __restrict__ Vbase, int key0,
    int quad, int l15, int s0b, int s1b, bool lowsel,
    const bf16x8& qa0, const bf16x8& qa1, const bf16x8& qb0, const bf16x8& qb1,
    f32x4 (&oa)[4], f32x4 (&ob)[4], float& la, float& lb)
{
    // V for THIS step: issued before QK^T, consumed after softmax (covered).
    const bf16_t* vp = Vbase + key0;
    const bf16x8 vf0 = ld8(vp);
    const bf16x8 vf1 = ld8(vp + (size_t)16 * 2048);
    const bf16x8 vf2 = ld8(vp + (size_t)32 * 2048);
    const bf16x8 vf3 = ld8(vp + (size_t)48 * 2048);

    const f32x4 Z = (f32x4){0.f, 0.f, 0.f, 0.f};
    f32x4 s0a = Z, s1a = Z, s0b_ = Z, s1b_ = Z;
    // swapped operands: C[row=key (quad*4+r)][col=query (l15)]
    s0a = MFMA16(kf.k00, qa0, s0a); s0a = MFMA16(kf.k01, qa1, s0a);
    s0b_ = MFMA16(kf.k00, qb0, s0b_); s0b_ = MFMA16(kf.k01, qb1, s0b_);
    if (!DIAG) {
        s1a = MFMA16(kf.k10, qa0, s1a); s1a = MFMA16(kf.k11, qa1, s1a);
    }
    s1b_ = MFMA16(kf.k10, qb0, s1b_); s1b_ = MFMA16(kf.k11, qb1, s1b_);

    bf16x4 pa0, pa1, pb0, pb1;
    if (DIAG) {
        pa0 = expq_m(s0a, la, quad, l15);
        pa1 = (bf16x4){(bf16_t)0.f, (bf16_t)0.f, (bf16_t)0.f, (bf16_t)0.f};
        pb0 = expq(s0b_, lb);
        pb1 = expq_m(s1b_, lb, quad, l15);
    } else {
        pa0 = expq(s0a, la); pa1 = expq(s1a, la);
        pb0 = expq(s0b_, lb); pb1 = expq(s1b_, lb);
    }

    const bf16x8 pfa = xpose(pa0, pa1, s0b, s1b, lowsel);
    const bf16x8 pfb = xpose(pb0, pb1, s0b, s1b, lowsel);

    oa[0] = MFMA16(pfa, vf0, oa[0]); ob[0] = MFMA16(pfb, vf0, ob[0]);
    oa[1] = MFMA16(pfa, vf1, oa[1]); ob[1] = MFMA16(pfb, vf1, ob[1]);
    oa[2] = MFMA16(pfa, vf2, oa[2]); ob[2] = MFMA16(pfb, vf2, ob[2]);
    oa[3] = MFMA16(pfa, vf3, oa[3]); ob[3] = MFMA16(pfb, vf3, ob[3]);
}

__global__ __launch_bounds__(128) void attn_kernel(
    const bf16_t* __restrict__ qk, const bf16_t* __restrict__ vt,
    bf16_t* __restrict__ out)
{
    __shared__ float mrg[64][34];   // pair partial merge (o:32, l:2)

    const int t    = threadIdx.x;
    const int par  = t >> 6;        // split-K parity (wave 0/1)
    const int lane = t & 63;
    const int quad = lane >> 4;
    const int l15  = lane & 15;

    const int bx = blockIdx.x;      // 0..4095
    const int u  = bx & 255;        // blocks aliasing mod 256 -> same CU
    const int v_ = bx >> 8;         // 0..15

    const int bh = ((u & 15) << 2) | (v_ & 3);   // 0..63, XCD-affine
    const int c  = u >> 4;                       // 0..15
    const int q2 = v_ >> 2;                      // 0..3
    const int cc = (q2 & 1) ? (15 - c) : c;
    const int qt = (q2 << 4) | cc;               // per-CU sum = 126 (const)
    const int b  = bh >> 4;
    const int h  = bh & 15;
    const int q0 = qt << 5;

    // bpermute source lanes (byte indices)
    const int s0b = ((((quad << 1)) & 3) * 16 + l15) << 2;
    const int s1b = ((((quad << 1) + 1) & 3) * 16 + l15) << 2;
    const bool lowsel = quad < 2;

    const bf16_t* Qp = qk + (size_t)(b * 2048 + q0 + l15) * 2048 + h * 64 + quad * 8;
    const bf16x8 qa0 = ld8(Qp);
    const bf16x8 qa1 = ld8(Qp + 32);
    const bf16x8 qb0 = ld8(Qp + (size_t)16 * 2048);
    const bf16x8 qb1 = ld8(Qp + (size_t)16 * 2048 + 32);

    const bf16_t* Kbase = qk + (size_t)(b * 2048 + l15) * 2048 + 1024 + h * 64 + quad * 8;
    const bf16_t* Vbase = vt + ((size_t)bh * 64 + l15) * 2048 + quad * 8;

    f32x4 oa[4], ob[4];
#pragma unroll
    for (int v = 0; v < 4; ++v) {
        oa[v] = (f32x4){0.f, 0.f, 0.f, 0.f};
        ob[v] = (f32x4){0.f, 0.f, 0.f, 0.f};
    }
    float la = 0.f, lb = 0.f;

    // this wave's tiles: kb = par, par+2, ... (< qt), plus diag if qt%2==par
    const bool dg = ((qt & 1) == par);
    int kb = par;
    if (kb < qt || dg) {
        Kfrag kc = ldk(Kbase, ((kb < qt) ? kb : qt) << 5);
        while (kb < qt) {
            const int nk = (kb + 2 < qt) ? (kb + 2) : qt;   // over-read safe
            Kfrag kn = ldk(Kbase, nk << 5);
            attn_step<0>(kc, Vbase, kb << 5, quad, l15, s0b, s1b, lowsel,
                         qa0, qa1, qb0, qb1, oa, ob, la, lb);
            kc = kn;
            kb += 2;
        }
        if (dg)
            attn_step<1>(kc, Vbase, qt << 5, quad, l15, s0b, s1b, lowsel,
                         qa0, qa1, qb0, qb1, oa, ob, la, lb);
    }

    // merge pair partials through LDS (additive: no rescale)
    float* m = &mrg[lane][0];
    if (par == 1) {
#pragma unroll
        for (int v = 0; v < 4; ++v)
#pragma unroll
            for (int r = 0; r < 4; ++r) {
                m[v * 4 + r]      = oa[v][r];
                m[16 + v * 4 + r] = ob[v][r];
            }
        m[32] = la; m[33] = lb;
    }
    __syncthreads();
    if (par == 1) return;

#pragma unroll
    for (int v = 0; v < 4; ++v)
#pragma unroll
        for (int r = 0; r < 4; ++r) {
            oa[v][r] += m[v * 4 + r];
            ob[v][r] += m[16 + v * 4 + r];
        }
    la += m[32]; lb += m[33];

    // l: sum the 4 quad replicas (lanes i, i+16, i+32, i+48)
    la += __shfl_xor(la, 16); la += __shfl_xor(la, 32);
    lb += __shfl_xor(lb, 16); lb += __shfl_xor(lb, 32);
    const float inva = 1.0f / la;
    const float invb = 1.0f / lb;

    const size_t obase = (size_t)(b * 2048 + q0 + quad * 4) * 1024 + h * 64 + l15;
#pragma unroll
    for (int r = 0; r < 4; ++r) {
        const float ia = __shfl(inva, quad * 4 + r);
        const float ib = __shfl(invb, quad * 4 + r);
#pragma unroll
        for (int v = 0; v < 4; ++v) {
            out[obase + (size_t)r * 1024 + v * 16]        = (bf16_t)(oa[v][r] * ia);
            out[obase + (size_t)(16 + r) * 1024 + v * 16] = (bf16_t)(ob[v][r] * ib);
        }
    }
}

// fp32-visible stamp if the workspace is too small.
__global__ void ws_check_kernel(float* out, int code) {
    if (code != 0 && threadIdx.x == 0) out[0] = (float)code;
}

// ---------------------------------------------------------------------------
extern "C" void kernel_launch(void* const* d_in, const int* in_sizes, int n_in,
                              void* d_out, int out_size, void* d_ws, size_t ws_size,
                              hipStream_t stream)
{
    const void* x    = d_in[0];   // [4,2048,1024]
    const void* wqkv = d_in[1];   // [3072,1024]
    const void* wout = d_in[2];   // [1024,1024]

    // ws: qk 32MB | vt 16MB | attnbuf 16MB = 64MB
    bf16_t* qkbuf   = (bf16_t*)d_ws;
    bf16_t* vtbuf   = qkbuf + (size_t)8192 * 2048;
    bf16_t* attnbuf = vtbuf + (size_t)64 * 64 * 2048;
    float*  outp    = (float*)d_out;

    // scratch aliases (see buffer plan at top)
    bf16_t* xb  = attnbuf;            // 16MB, dead before attn writes attnbuf
    bf16_t* wqb = (bf16_t*)d_out;     // 6MB in d_out, dead before gemm2 writes
    bf16_t* wob = vtbuf;              // 2MB in vt region, converted after attn

    const int wsBad = (ws_size < (size_t)64 * 1024 * 1024) ? 512 : 0;

    // 0) convert x, W_qkv to bf16 (probe handles fp32 or bf16 inputs)
    cvt_big_kernel<<<5632, 256, 0, stream>>>(x, wqkv, xb, wqb);

    // 1) QKV projection (fast bf16 path): split Q|K + V^T
    gemm_bt_lds<1><<<dim3(24, 64), 256, 0, stream>>>(
        xb, wqb, qkbuf, vtbuf, 8192, 3072, 1024);

    // 2) causal flash attention: 4096 pair-blocks x 128 threads
    attn_kernel<<<4096, 128, 0, stream>>>(qkbuf, vtbuf, attnbuf);

    // 3) convert W_out (vt region now dead)
    cvt_small_kernel<<<512, 256, 0, stream>>>(wout, wob);

    // 4) output projection -> fp32 d_out (overwrites wqb scratch)
    gemm_bt_lds<0><<<dim3(8, 64), 256, 0, stream>>>(
        attnbuf, wob, outp, nullptr, 8192, 1024, 1024);

    ws_check_kernel<<<1, 64, 0, stream>>>(outp, wsBad);
}

// Round 5
// 339.187 us; speedup vs baseline: 1.1935x; 1.0725x over previous
//
#include <hip/hip_runtime.h>
#include <hip/hip_bf16.h>
#include <stdint.h>

// B=4, S=2048, D=1024, H=16, hd=64.
// Inputs fp32 or bf16 (wave-ballot probe in cvt kernels only); downstream is
// pure bf16. OUTPUT IS FLOAT32.
//
// Buffer plan (64MB ws + d_out-as-scratch):
//   ws:    qk 32MB | vt 16MB | attnbuf 16MB
//   xb  (16MB bf16) -> attnbuf region  (dead before attn writes it)
//   wqb ( 6MB bf16) -> d_out scratch   (read by gemm1 only; gemm1 writes ws)
//   wob ( 2MB bf16) -> vtbuf region    (converted after attn; vt dead then)

typedef __bf16 bf16_t;
typedef __attribute__((ext_vector_type(8))) __bf16 bf16x8;
typedef __attribute__((ext_vector_type(4))) __bf16 bf16x4;
typedef __attribute__((ext_vector_type(4))) float f32x4;

#define LOG2E 1.44269504088896340736f
#define SCLF (0.125f * LOG2E)
#define MFMA16(a, b, c) __builtin_amdgcn_mfma_f32_16x16x32_bf16(a, b, c, 0, 0, 0)

__device__ __forceinline__ bf16x8 ld8(const bf16_t* p) {
    return *(const bf16x8*)p;
}
__device__ __forceinline__ bf16x8 cvt8(const float* p) {
    f32x4 a = *(const f32x4*)p;
    f32x4 b = *(const f32x4*)(p + 4);
    bf16x8 r;
    r[0] = (bf16_t)a[0]; r[1] = (bf16_t)a[1]; r[2] = (bf16_t)a[2]; r[3] = (bf16_t)a[3];
    r[4] = (bf16_t)b[0]; r[5] = (bf16_t)b[1]; r[6] = (bf16_t)b[2]; r[7] = (bf16_t)b[3];
    return r;
}

// dtype probe, wave-cooperative: ONE coalesced load per lane + ballot.
// (R4's per-thread 64-load version cost ~92M load insts across cvt grid.)
__device__ __forceinline__ bool probe_f32_wave(const void* w) {
    const uint16_t* u = (const uint16_t*)w;
    const int lane = threadIdx.x & 63;
    const int e = (u[lane] >> 7) & 0xFF;
    const unsigned long long m = __ballot(e >= 96 && e <= 150);
    return __popcll(m) < 56;
}

// async global->LDS, 16B per lane. LDS dest: wave-uniform base + lane*16.
__device__ __forceinline__ void gll16(const bf16_t* g, bf16_t* l) {
    __builtin_amdgcn_global_load_lds(
        (const __attribute__((address_space(1))) void*)g,
        (__attribute__((address_space(3))) void*)l, 16, 0, 0);
}

// ---------------------------------------------------------------------------
// Input conversion (fp32->bf16, or bf16 copy), 8 elems/thread.
// big: x (1048576 chunks) + W_qkv (393216) = 5632 blocks x 256.
// small: W_out (131072 chunks) = 512 blocks x 256.
// ---------------------------------------------------------------------------
__global__ __launch_bounds__(256) void cvt_big_kernel(
    const void* __restrict__ x, const void* __restrict__ wq,
    bf16_t* __restrict__ xb, bf16_t* __restrict__ wqb)
{
    const int gid = blockIdx.x * 256 + threadIdx.x;
    const void* src;
    bf16_t* dst;
    int off;
    if (gid < 1048576) { src = x;  dst = xb;  off = gid; }
    else               { src = wq; dst = wqb; off = gid - 1048576; }
    const bool f32 = probe_f32_wave(src);
    const bf16x8 v = f32 ? cvt8((const float*)src + (size_t)off * 8)
                         : ld8((const bf16_t*)src + (size_t)off * 8);
    *(bf16x8*)(dst + (size_t)off * 8) = v;
}

__global__ __launch_bounds__(256) void cvt_small_kernel(
    const void* __restrict__ wo, bf16_t* __restrict__ wob)
{
    const int off = blockIdx.x * 256 + threadIdx.x;
    const bool f32 = probe_f32_wave(wo);
    const bf16x8 v = f32 ? cvt8((const float*)wo + (size_t)off * 8)
                         : ld8((const bf16_t*)wo + (size_t)off * 8);
    *(bf16x8*)(wob + (size_t)off * 8) = v;
}

// ---------------------------------------------------------------------------
// GEMM (pure bf16): C = A[M,K] @ B[N,K]^T, 128x128 tile, BK=32,
// global_load_lds width-16 staging (m97 structure).
// EPI==0: C float*, plain [M,N]. EPI==1: C bf16* Q|K split + VT scatter.
// ---------------------------------------------------------------------------
template <int EPI>
__global__ __launch_bounds__(256) void gemm_bt_lds(
    const bf16_t* __restrict__ A, const bf16_t* __restrict__ B,
    void* __restrict__ C, bf16_t* __restrict__ VT,
    int M, int N, int K)
{
    __shared__ __align__(16) bf16_t lsA[128 * 32];
    __shared__ __align__(16) bf16_t lsB[128 * 32];

    const int t    = threadIdx.x;
    const int lane = t & 63;
    const int wid  = t >> 6;
    const int quad = lane >> 4;
    const int l15  = lane & 15;
    const int wm   = (wid & 1) * 64;
    const int wn   = (wid >> 1) * 64;
    const int m0   = blockIdx.y * 128;
    const int n0   = blockIdx.x * 128;

    // thread t stages 16B: row (t>>2), col (t&3)*8 -> LDS byte t*16 (linear)
    const bf16_t* Ar = A + (size_t)(m0 + (t >> 2)) * K + (t & 3) * 8;
    const bf16_t* Br = B + (size_t)(n0 + (t >> 2)) * K + (t & 3) * 8;
    bf16_t* la = lsA + t * 8;
    bf16_t* lb = lsB + t * 8;

    f32x4 acc[4][4];
#pragma unroll
    for (int i = 0; i < 4; ++i)
#pragma unroll
        for (int j = 0; j < 4; ++j) acc[i][j] = (f32x4){0.f, 0.f, 0.f, 0.f};

    for (int k0 = 0; k0 < K; k0 += 32) {
        __syncthreads();   // previous tile's readers done
        gll16(Ar + k0, la);
        gll16(Ar + (size_t)64 * K + k0, la + 2048);
        gll16(Br + k0, lb);
        gll16(Br + (size_t)64 * K + k0, lb + 2048);
        __syncthreads();   // compiler drains vmcnt before s_barrier: tile visible

        bf16x8 af[4], bfr[4];
#pragma unroll
        for (int i = 0; i < 4; ++i)
            af[i] = ld8(lsA + (wm + i * 16 + l15) * 32 + quad * 8);
#pragma unroll
        for (int j = 0; j < 4; ++j)
            bfr[j] = ld8(lsB + (wn + j * 16 + l15) * 32 + quad * 8);
#pragma unroll
        for (int i = 0; i < 4; ++i)
#pragma unroll
            for (int j = 0; j < 4; ++j)
                acc[i][j] = MFMA16(af[i], bfr[j], acc[i][j]);
    }

#pragma unroll
    for (int i = 0; i < 4; ++i) {
        const int row = m0 + wm + i * 16 + quad * 4;
#pragma unroll
        for (int j = 0; j < 4; ++j) {
            const int col = n0 + wn + j * 16 + l15;
#pragma unroll
            for (int r = 0; r < 4; ++r) {
                const int rr = row + r;
                if (EPI == 0) {
                    ((float*)C)[(size_t)rr * N + col] = acc[i][j][r];
                } else {
                    const bf16_t v = (bf16_t)acc[i][j][r];
                    if (col < 2048) {
                        ((bf16_t*)C)[(size_t)rr * 2048 + col] = v;
                    } else {
                        const int c2 = col - 2048;
                        const int h = c2 >> 6, d = c2 & 63;
                        const int b = rr >> 11, s = rr & 2047;
                        VT[((size_t)((b << 4) + h) * 64 + d) * 2048 + s] = v;
                    }
                }
            }
        }
    }
}

// ---------------------------------------------------------------------------
// Flash attention (causal), NO-RESCALE, QBLK=32/wave — R2 task structure
// (best measured: 142us), plus DEFERRED-PV software pipeline:
// iteration kb issues PV(P[kb-1], V[kb-1]) BEFORE QK(kb); PV's MFMAs are
// independent of this step's exp/xpose, so the cross-iteration serial chain
// shrinks from {QK->exp->xpose->PV} to {QK->exp->xpose}, and V[kb] gets a
// full iteration of load slack. Same math; P/V double-buffered in regs.
// ---------------------------------------------------------------------------
struct Kfrag { bf16x8 k00, k01, k10, k11; };
struct Vfrag { bf16x8 v0, v1, v2, v3; };

__device__ __forceinline__ Kfrag ldk(const bf16_t* Kbase, int key0) {
    const bf16_t* kp = Kbase + (size_t)key0 * 2048;
    Kfrag f;
    f.k00 = ld8(kp);
    f.k01 = ld8(kp + 32);
    f.k10 = ld8(kp + (size_t)16 * 2048);
    f.k11 = ld8(kp + (size_t)16 * 2048 + 32);
    return f;
}
__device__ __forceinline__ Vfrag ldv(const bf16_t* Vbase, int key0) {
    const bf16_t* vp = Vbase + key0;
    Vfrag f;
    f.v0 = ld8(vp);
    f.v1 = ld8(vp + (size_t)16 * 2048);
    f.v2 = ld8(vp + (size_t)32 * 2048);
    f.v3 = ld8(vp + (size_t)48 * 2048);
    return f;
}

__device__ __forceinline__ bf16x4 expq(f32x4 s, float& lsum) {
    bf16x4 r;
#pragma unroll
    for (int i = 0; i < 4; ++i) {
        const float e = exp2f(s[i] * SCLF);
        r[i] = (bf16_t)e;
        lsum += (float)r[i];
    }
    return r;
}
__device__ __forceinline__ bf16x4 expq_m(f32x4 s, float& lsum, int quad, int l15) {
    bf16x4 r;
#pragma unroll
    for (int i = 0; i < 4; ++i) {
        const float e = (quad * 4 + i <= l15) ? exp2f(s[i] * SCLF) : 0.f;
        r[i] = (bf16_t)e;
        lsum += (float)r[i];
    }
    return r;
}

typedef union { bf16x4 h; int u[2]; } pk2;
typedef union { int u[4]; bf16x8 v; } pk4u;

// C-layout (lane=query l15, keys quad*4+r in p0 / 16+quad*4+r in p1) ->
// A-layout (lane=query l15, keys quad*8..quad*8+7). Lane permutation among
// {i, i+16, i+32, i+48}: 8 bpermutes + 4 selects.
__device__ __forceinline__ bf16x8 xpose(bf16x4 p0, bf16x4 p1, int s0b, int s1b, bool lowsel) {
    pk2 a, b;
    a.h = p0; b.h = p1;
    const int x0 = __builtin_amdgcn_ds_bpermute(s0b, a.u[0]);
    const int y0 = __builtin_amdgcn_ds_bpermute(s0b, b.u[0]);
    const int x1 = __builtin_amdgcn_ds_bpermute(s0b, a.u[1]);
    const int y1 = __builtin_amdgcn_ds_bpermute(s0b, b.u[1]);
    const int x2 = __builtin_amdgcn_ds_bpermute(s1b, a.u[0]);
    const int y2 = __builtin_amdgcn_ds_bpermute(s1b, b.u[0]);
    const int x3 = __builtin_amdgcn_ds_bpermute(s1b, a.u[1]);
    const int y3 = __builtin_amdgcn_ds_bpermute(s1b, b.u[1]);
    pk4u r;
    r.u[0] = lowsel ? x0 : y0;
    r.u[1] = lowsel ? x1 : y1;
    r.u[2] = lowsel ? x2 : y2;
    r.u[3] = lowsel ? x3 : y3;
    return r.v;
}

// QK^T + softmax + transpose for one 32-key tile -> P fragments (pfa, pfb).
template <int DIAG>
__device__ __forceinline__ void qk_phase(
    const Kfrag& kf, int quad, int l15, int s0b, int s1b, bool lowsel,
    const bf16x8& qa0, const bf16x8& qa1, const bf16x8& qb0, const bf16x8& qb1,
    bf16x8& pfa, bf16x8& pfb, float& la, float& lb)
{
    const f32x4 Z = (f32x4){0.f, 0.f, 0.f, 0.f};
    f32x4 s0a = Z, s1a = Z, s0b_ = Z, s1b_ = Z;
    // swapped operands: C[row=key (quad*4+r)][col=query (l15)]
    s0a = MFMA16(kf.k00, qa0, s0a); s0a = MFMA16(kf.k01, qa1, s0a);
    s0b_ = MFMA16(kf.k00, qb0, s0b_); s0b_ = MFMA16(kf.k01, qb1, s0b_);
    if (!DIAG) {
        s1a = MFMA16(kf.k10, qa0, s1a); s1a = MFMA16(kf.k11, qa1, s1a);
    }
    s1b_ = MFMA16(kf.k10, qb0, s1b_); s1b_ = MFMA16(kf.k11, qb1, s1b_);

    bf16x4 pa0, pa1, pb0, pb1;
    if (DIAG) {
        pa0 = expq_m(s0a, la, quad, l15);
        pa1 = (bf16x4){(bf16_t)0.f, (bf16_t)0.f, (bf16_t)0.f, (bf16_t)0.f};
        pb0 = expq(s0b_, lb);
        pb1 = expq_m(s1b_, lb, quad, l15);
    } else {
        pa0 = expq(s0a, la); pa1 = expq(s1a, la);
        pb0 = expq(s0b_, lb); pb1 = expq(s1b_, lb);
    }
    pfa = xpose(pa0, pa1, s0b, s1b, lowsel);
    pfb = xpose(pb0, pb1, s0b, s1b, lowsel);
}

__device__ __forceinline__ void pv(
    const bf16x8& pfa, const bf16x8& pfb, const Vfrag& v,
    f32x4 (&oa)[4], f32x4 (&ob)[4])
{
    oa[0] = MFMA16(pfa, v.v0, oa[0]); ob[0] = MFMA16(pfb, v.v0, ob[0]);
    oa[1] = MFMA16(pfa, v.v1, oa[1]); ob[1] = MFMA16(pfb, v.v1, ob[1]);
    oa[2] = MFMA16(pfa, v.v2, oa[2]); ob[2] = MFMA16(pfb, v.v2, ob[2]);
    oa[3] = MFMA16(pfa, v.v3, oa[3]); ob[3] = MFMA16(pfb, v.v3, ob[3]);
}

__global__ __launch_bounds__(256, 4) void attn_kernel(
    const bf16_t* __restrict__ qk, const bf16_t* __restrict__ vt,
    bf16_t* __restrict__ out)
{
    const int t    = threadIdx.x;
    const int wid  = t >> 6;
    const int lane = t & 63;
    const int quad = lane >> 4;
    const int l15  = lane & 15;

    const int bx = blockIdx.x;                   // 0..1023 (R2 mapping)
    const int u  = bx & 255;
    const int v_ = bx >> 8;                      // 0..3
    const int bh = ((u & 15) << 2) | wid;        // 0..63, XCD-affine
    const int c  = u >> 4;                       // 0..15
    const int bs = (v_ & 1) ? (31 - c) : c;
    const int qt = bs + ((v_ >> 1) << 5);        // per-CU/SIMD sum constant
    const int b  = bh >> 4;
    const int h  = bh & 15;
    const int q0 = qt << 5;

    // bpermute source lanes (byte indices)
    const int s0b = ((((quad << 1)) & 3) * 16 + l15) << 2;
    const int s1b = ((((quad << 1) + 1) & 3) * 16 + l15) << 2;
    const bool lowsel = quad < 2;

    const bf16_t* Qp = qk + (size_t)(b * 2048 + q0 + l15) * 2048 + h * 64 + quad * 8;
    const bf16x8 qa0 = ld8(Qp);
    const bf16x8 qa1 = ld8(Qp + 32);
    const bf16x8 qb0 = ld8(Qp + (size_t)16 * 2048);
    const bf16x8 qb1 = ld8(Qp + (size_t)16 * 2048 + 32);

    const bf16_t* Kbase = qk + (size_t)(b * 2048 + l15) * 2048 + 1024 + h * 64 + quad * 8;
    const bf16_t* Vbase = vt + ((size_t)bh * 64 + l15) * 2048 + quad * 8;

    f32x4 oa[4], ob[4];
#pragma unroll
    for (int v = 0; v < 4; ++v) {
        oa[v] = (f32x4){0.f, 0.f, 0.f, 0.f};
        ob[v] = (f32x4){0.f, 0.f, 0.f, 0.f};
    }
    float la = 0.f, lb = 0.f;

    Kfrag kc = ldk(Kbase, 0);
    Vfrag vc = ldv(Vbase, 0);
    bf16x8 pfa, pfb;

    if (qt > 0) {
        Kfrag kn = ldk(Kbase, 32);               // prefetch K1
        qk_phase<0>(kc, quad, l15, s0b, s1b, lowsel,
                    qa0, qa1, qb0, qb1, pfa, pfb, la, lb);   // P0
        kc = kn;
        for (int kb = 1; kb < qt; ++kb) {
            Kfrag knn = ldk(Kbase, (kb + 1) << 5);   // prefetch K[kb+1]
            Vfrag vn  = ldv(Vbase, kb << 5);         // V[kb], used next iter
            pv(pfa, pfb, vc, oa, ob);                // PV[kb-1] (indep of exp)
            qk_phase<0>(kc, quad, l15, s0b, s1b, lowsel,
                        qa0, qa1, qb0, qb1, pfa, pfb, la, lb);  // P[kb]
            kc = knn; vc = vn;
        }
        Vfrag vn = ldv(Vbase, qt << 5);              // V[qt] (diag)
        pv(pfa, pfb, vc, oa, ob);                    // PV[qt-1]
        qk_phase<1>(kc, quad, l15, s0b, s1b, lowsel,
                    qa0, qa1, qb0, qb1, pfa, pfb, la, lb);      // P[qt] diag
        vc = vn;
    } else {
        qk_phase<1>(kc, quad, l15, s0b, s1b, lowsel,
                    qa0, qa1, qb0, qb1, pfa, pfb, la, lb);
    }
    pv(pfa, pfb, vc, oa, ob);                        // flush diag PV

    // l: sum the 4 quad replicas (lanes i, i+16, i+32, i+48)
    la += __shfl_xor(la, 16); la += __shfl_xor(la, 32);
    lb += __shfl_xor(lb, 16); lb += __shfl_xor(lb, 32);
    const float inva = 1.0f / la;
    const float invb = 1.0f / lb;

    const size_t obase = (size_t)(b * 2048 + q0 + quad * 4) * 1024 + h * 64 + l15;
#pragma unroll
    for (int r = 0; r < 4; ++r) {
        const float ia = __shfl(inva, quad * 4 + r);
        const float ib = __shfl(invb, quad * 4 + r);
#pragma unroll
        for (int v = 0; v < 4; ++v) {
            out[obase + (size_t)r * 1024 + v * 16]        = (bf16_t)(oa[v][r] * ia);
            out[obase + (size_t)(16 + r) * 1024 + v * 16] = (bf16_t)(ob[v][r] * ib);
        }
    }
}

// fp32-visible stamp if the workspace is too small.
__global__ void ws_check_kernel(float* out, int code) {
    if (code != 0 && threadIdx.x == 0) out[0] = (float)code;
}

// ---------------------------------------------------------------------------
extern "C" void kernel_launch(void* const* d_in, const int* in_sizes, int n_in,
                              void* d_out, int out_size, void* d_ws, size_t ws_size,
                              hipStream_t stream)
{
    const void* x    = d_in[0];   // [4,2048,1024]
    const void* wqkv = d_in[1];   // [3072,1024]
    const void* wout = d_in[2];   // [1024,1024]

    // ws: qk 32MB | vt 16MB | attnbuf 16MB = 64MB
    bf16_t* qkbuf   = (bf16_t*)d_ws;
    bf16_t* vtbuf   = qkbuf + (size_t)8192 * 2048;
    bf16_t* attnbuf = vtbuf + (size_t)64 * 64 * 2048;
    float*  outp    = (float*)d_out;

    // scratch aliases (see buffer plan at top)
    bf16_t* xb  = attnbuf;            // 16MB, dead before attn writes attnbuf
    bf16_t* wqb = (bf16_t*)d_out;     // 6MB in d_out, dead before gemm2 writes
    bf16_t* wob = vtbuf;              // 2MB in vt region, converted after attn

    const int wsBad = (ws_size < (size_t)64 * 1024 * 1024) ? 512 : 0;

    // 0) convert x, W_qkv to bf16 (ballot probe: fp32 or bf16 inputs)
    cvt_big_kernel<<<5632, 256, 0, stream>>>(x, wqkv, xb, wqb);

    // 1) QKV projection (bf16 fast path): split Q|K + V^T
    gemm_bt_lds<1><<<dim3(24, 64), 256, 0, stream>>>(
        xb, wqb, qkbuf, vtbuf, 8192, 3072, 1024);

    // 2) causal flash attention: 1024 blocks x 4 waves (R2 structure)
    attn_kernel<<<1024, 256, 0, stream>>>(qkbuf, vtbuf, attnbuf);

    // 3) convert W_out (vt region now dead)
    cvt_small_kernel<<<512, 256, 0, stream>>>(wout, wob);

    // 4) output projection -> fp32 d_out (overwrites wqb scratch)
    gemm_bt_lds<0><<<dim3(8, 64), 256, 0, stream>>>(
        attnbuf, wob, outp, nullptr, 8192, 1024, 1024);

    ws_check_kernel<<<1, 64, 0, stream>>>(outp, wsBad);
}